// Round 2
// baseline (759.624 us; speedup 1.0000x reference)
//
#include <hip/hip_runtime.h>
#include <math.h>

#define HIDN 64
#define NCLS_K 32
#define INDIM 256
#define BSHIFT 7            // bucket = src >> 7  (128 src rows per bucket)
#define MAXBUCK 1024        // supports N <= 131072
#define BUCK_CAP 4096       // max edges per bucket (mean 2048, std ~45)

// ---------------- per-node projections: pa = h.att_w[:64], pb = h.att_w[64:]
__global__ __launch_bounds__(256) void proj_kernel(const float* __restrict__ hid,
    const float* __restrict__ attw, float* __restrict__ pa, float* __restrict__ pb, int n) {
  int wid  = (blockIdx.x * blockDim.x + threadIdx.x) >> 6;
  int lane = threadIdx.x & 63;
  if (wid >= n) return;
  float v = hid[(size_t)wid * HIDN + lane];
  float a = v * attw[lane];
  float b = v * attw[HIDN + lane];
  #pragma unroll
  for (int off = 32; off >= 1; off >>= 1) {
    a += __shfl_xor(a, off, 64);
    b += __shfl_xor(b, off, 64);
  }
  if (lane == 0) { pa[wid] = a; pb[wid] = b; }
}

// ---------------- CSR build pass A: bucket histogram
__global__ __launch_bounds__(256) void hist_kernel(const int* __restrict__ src,
    int* __restrict__ bcnt, int e, int nb) {
  __shared__ int h[MAXBUCK];
  for (int j = threadIdx.x; j < MAXBUCK; j += 256) h[j] = 0;
  __syncthreads();
  for (int i = blockIdx.x * 256 + threadIdx.x; i < e; i += gridDim.x * 256)
    atomicAdd(&h[src[i] >> BSHIFT], 1);
  __syncthreads();
  for (int j = threadIdx.x; j < nb; j += 256)
    if (h[j]) atomicAdd(&bcnt[j], h[j]);
}

// ---------------- CSR build: scan bucket counts (single block)
__global__ __launch_bounds__(1024) void scan_buckets(const int* __restrict__ bcnt,
    int* __restrict__ bbase, int* __restrict__ rowp, int nb, int n, int e) {
  __shared__ int sm[1024];
  int tid = threadIdx.x;
  int v = (tid < nb) ? bcnt[tid] : 0;
  sm[tid] = v;
  __syncthreads();
  for (int off = 1; off < 1024; off <<= 1) {
    int t = (tid >= off) ? sm[tid - off] : 0;
    __syncthreads();
    sm[tid] += t;
    __syncthreads();
  }
  if (tid < nb) bbase[tid] = sm[tid] - v;   // exclusive
  if (tid == 0) { bbase[nb] = e; rowp[n] = e; }
}

// ---------------- CSR build pass B: scatter (src,dst) pairs into bucket regions
__global__ __launch_bounds__(256) void scatter_pairs(const int* __restrict__ src,
    const int* __restrict__ dst, const int* __restrict__ bbase,
    int* __restrict__ bcur, int2* __restrict__ pairs, int e) {
  int i = blockIdx.x * 256 + threadIdx.x;
  if (i < e) {
    int s = src[i];
    int b = s >> BSHIFT;
    int pos = bbase[b] + atomicAdd(&bcur[b], 1);
    pairs[pos] = make_int2(s, dst[i]);
  }
}

// ---------------- CSR build pass C: per-bucket LDS counting sort -> rowp, dstc
__global__ __launch_bounds__(256) void build_csr(const int2* __restrict__ pairs,
    const int* __restrict__ bbase, int* __restrict__ rowp,
    int* __restrict__ dstc, int n) {
  __shared__ int hist[128];
  __shared__ int cur[128];
  __shared__ int ord[BUCK_CAP];
  int b = blockIdx.x;
  int tid = threadIdx.x;
  int base = bbase[b];
  int m = bbase[b + 1] - base;
  if (tid < 128) hist[tid] = 0;
  __syncthreads();
  for (int i = tid; i < m; i += 256) atomicAdd(&hist[pairs[base + i].x & 127], 1);
  __syncthreads();
  int own = (tid < 128) ? hist[tid] : 0;
  for (int off = 1; off < 128; off <<= 1) {          // inclusive scan of 128
    int t = (tid < 128 && tid >= off) ? hist[tid - off] : 0;
    __syncthreads();
    if (tid < 128) hist[tid] += t;
    __syncthreads();
  }
  if (tid < 128) {
    int excl = hist[tid] - own;
    cur[tid] = excl;
    int s = (b << BSHIFT) + tid;
    if (s < n) rowp[s] = base + excl;
  }
  __syncthreads();
  for (int i = tid; i < m; i += 256) {
    int2 pr = pairs[base + i];
    int pos = atomicAdd(&cur[pr.x & 127], 1);
    ord[pos] = pr.y;
  }
  __syncthreads();
  for (int i = tid; i < m; i += 256) dstc[base + i] = ord[i];
}

// ---------------- per-row (src-segmented) edge softmax, wave per row
__global__ __launch_bounds__(256) void att_softmax(const float* __restrict__ pa,
    const float* __restrict__ pb, const int* __restrict__ dstc,
    const int* __restrict__ rowp, float* __restrict__ attv, int n) {
  int wid  = (blockIdx.x * blockDim.x + threadIdx.x) >> 6;
  int lane = threadIdx.x & 63;
  if (wid >= n) return;
  int start = rowp[wid], end = rowp[wid + 1];
  if (start == end) return;
  float pai = pa[wid];
  float m = -3.0e38f;
  for (int base = start; base < end; base += 64) {
    int e = base + lane;
    float s = -3.0e38f;
    if (e < end) {
      float v = pai + pb[dstc[e]];
      s = v > 0.f ? v : 0.01f * v;        // leaky_relu slope 0.01
      attv[e] = s;
    }
    m = fmaxf(m, s);
  }
  #pragma unroll
  for (int off = 32; off >= 1; off >>= 1) m = fmaxf(m, __shfl_xor(m, off, 64));
  float sum = 0.f;
  for (int base = start; base < end; base += 64) {
    int e = base + lane;
    float ex = 0.f;
    if (e < end) { ex = expf(attv[e] - m); attv[e] = ex; }
    sum += ex;
  }
  #pragma unroll
  for (int off = 32; off >= 1; off >>= 1) sum += __shfl_xor(sum, off, 64);
  float inv = 1.f / sum;
  for (int base = start; base < end; base += 64) {
    int e = base + lane;
    if (e < end) attv[e] *= inv;
  }
}

// ---------------- tiled dense GEMM: X[n x TJ] = A[n x K] @ W[K x TJ]
// 128-row x TJ-col block tile, 4 x TN per-thread tile, KC=64 k-chunks in LDS.
template <int K, int TJ, int TN>
__global__ __launch_bounds__(256) void gemm_tiled(const float* __restrict__ A,
    const float* __restrict__ W, float* __restrict__ X, int n) {
  constexpr int KC = 64;
  constexpr int TR = 128;
  constexpr int CG = TJ / TN;                 // 8 column groups
  __shared__ float Hs[TR][KC + 1];            // +1 pad: conflict-free scalar reads
  __shared__ float Ws[KC][TJ];
  const int tid  = threadIdx.x;
  const int row0 = blockIdx.x * TR;
  const int tx = tid % CG;
  const int ty = tid / CG;                    // 0..31
  float acc[4][TN];
  #pragma unroll
  for (int i = 0; i < 4; ++i)
    #pragma unroll
    for (int j = 0; j < TN; ++j) acc[i][j] = 0.f;

  for (int kc = 0; kc < K; kc += KC) {
    #pragma unroll
    for (int p = 0; p < (TR * KC) / (4 * 256); ++p) {   // 8 float4 per thread
      int f = tid + p * 256;
      int r = f >> 4;
      int q = f & 15;
      float4 h4 = make_float4(0.f, 0.f, 0.f, 0.f);
      if (row0 + r < n)
        h4 = *reinterpret_cast<const float4*>(A + (size_t)(row0 + r) * K + kc + q * 4);
      Hs[r][q * 4 + 0] = h4.x;
      Hs[r][q * 4 + 1] = h4.y;
      Hs[r][q * 4 + 2] = h4.z;
      Hs[r][q * 4 + 3] = h4.w;
    }
    #pragma unroll
    for (int p = 0; p < (KC * TJ) / (4 * 256); ++p) {
      int f = tid + p * 256;
      reinterpret_cast<float4*>(&Ws[0][0])[f] =
          reinterpret_cast<const float4*>(W + (size_t)kc * TJ)[f];
    }
    __syncthreads();
    for (int kk = 0; kk < KC; ++kk) {
      float a0 = Hs[ty * 4 + 0][kk];
      float a1 = Hs[ty * 4 + 1][kk];
      float a2 = Hs[ty * 4 + 2][kk];
      float a3 = Hs[ty * 4 + 3][kk];
      float bb[TN];
      #pragma unroll
      for (int j = 0; j < TN; j += 4) {
        float4 b4 = *reinterpret_cast<const float4*>(&Ws[kk][tx * TN + j]);
        bb[j] = b4.x; bb[j + 1] = b4.y; bb[j + 2] = b4.z; bb[j + 3] = b4.w;
      }
      #pragma unroll
      for (int j = 0; j < TN; ++j) {
        acc[0][j] += a0 * bb[j];
        acc[1][j] += a1 * bb[j];
        acc[2][j] += a2 * bb[j];
        acc[3][j] += a3 * bb[j];
      }
    }
    __syncthreads();
  }
  #pragma unroll
  for (int i = 0; i < 4; ++i) {
    int r = row0 + ty * 4 + i;
    if (r < n) {
      #pragma unroll
      for (int j = 0; j < TN; j += 4) {
        float4 o = make_float4(acc[i][j], acc[i][j + 1], acc[i][j + 2], acc[i][j + 3]);
        *reinterpret_cast<float4*>(X + (size_t)r * TJ + tx * TN + j) = o;
      }
    }
  }
}

// ---------------- SpMM + ELU (+ fused log_softmax), wave/row, float4 gathers
template <int J, bool FINAL>
__global__ __launch_bounds__(256) void spmm_elu(const float4* __restrict__ Xv,
    const float* __restrict__ attv, const int* __restrict__ dstc,
    const int* __restrict__ rowp, float4* __restrict__ outv, int n) {
  constexpr int CW  = J / 4;            // float4 col groups: 16 (J=64) / 8 (J=32)
  constexpr int EPW = 64 / CW;          // edges in flight per step: 4 / 8
  int wid  = (blockIdx.x * blockDim.x + threadIdx.x) >> 6;
  int lane = threadIdx.x & 63;
  if (wid >= n) return;
  int start = rowp[wid], end = rowp[wid + 1];
  int col  = lane & (CW - 1);
  int esub = lane / CW;
  float4 acc0 = make_float4(0.f, 0.f, 0.f, 0.f);
  float4 acc1 = make_float4(0.f, 0.f, 0.f, 0.f);
  for (int base = start; base < end; base += 64) {
    int e = base + lane;
    float av = 0.f; int dv = 0;
    if (e < end) { av = attv[e]; dv = dstc[e]; }
    int cnt = min(64, end - base);
    for (int t = 0; t < cnt; t += 2 * EPW) {
      {
        int mi = t + esub;                 // always <= 63
        float bv = __shfl(av, mi);
        int   d  = __shfl(dv, mi);
        float4 x = Xv[(size_t)d * CW + col];
        acc0.x += bv * x.x; acc0.y += bv * x.y;
        acc0.z += bv * x.z; acc0.w += bv * x.w;
      }
      {
        int mi = t + EPW + esub;           // always <= 63; av=0 beyond cnt
        float bv = __shfl(av, mi);
        int   d  = __shfl(dv, mi);
        float4 x = Xv[(size_t)d * CW + col];
        acc1.x += bv * x.x; acc1.y += bv * x.y;
        acc1.z += bv * x.z; acc1.w += bv * x.w;
      }
    }
  }
  float4 acc = make_float4(acc0.x + acc1.x, acc0.y + acc1.y,
                           acc0.z + acc1.z, acc0.w + acc1.w);
  #pragma unroll
  for (int off = CW; off < 64; off <<= 1) {     // reduce across edge sub-groups
    acc.x += __shfl_xor(acc.x, off);
    acc.y += __shfl_xor(acc.y, off);
    acc.z += __shfl_xor(acc.z, off);
    acc.w += __shfl_xor(acc.w, off);
  }
  acc.x = acc.x > 0.f ? acc.x : (expf(acc.x) - 1.f);   // ELU
  acc.y = acc.y > 0.f ? acc.y : (expf(acc.y) - 1.f);
  acc.z = acc.z > 0.f ? acc.z : (expf(acc.z) - 1.f);
  acc.w = acc.w > 0.f ? acc.w : (expf(acc.w) - 1.f);
  if (!FINAL) {
    if (lane < CW) outv[(size_t)wid * CW + col] = acc;
  } else {
    float m = fmaxf(fmaxf(acc.x, acc.y), fmaxf(acc.z, acc.w));
    #pragma unroll
    for (int off = 1; off < CW; off <<= 1) m = fmaxf(m, __shfl_xor(m, off));
    float s = expf(acc.x - m) + expf(acc.y - m) + expf(acc.z - m) + expf(acc.w - m);
    #pragma unroll
    for (int off = 1; off < CW; off <<= 1) s += __shfl_xor(s, off);
    float lg = m + logf(s);
    acc.x -= lg; acc.y -= lg; acc.z -= lg; acc.w -= lg;
    if (lane < CW) outv[(size_t)wid * CW + col] = acc;
  }
}

extern "C" void kernel_launch(void* const* d_in, const int* in_sizes, int n_in,
                              void* d_out, int out_size, void* d_ws, size_t ws_size,
                              hipStream_t stream) {
  const float* features = (const float*)d_in[0];
  const float* hidden   = (const float*)d_in[1];
  const int*   adj      = (const int*)d_in[2];
  const float* W0       = (const float*)d_in[3];
  const float* W1       = (const float*)d_in[4];
  const float* W2       = (const float*)d_in[5];
  const float* attw     = (const float*)d_in[6];
  float* out = (float*)d_out;

  const int N = in_sizes[1] / HIDN;   // 100000
  const int E = in_sizes[2] / 2;      // 1600000
  const int* src = adj;
  const int* dst = adj + E;
  const int NBUCK = (N + 127) >> BSHIFT;            // 782
  const int NB2   = ((NBUCK + 15) / 16) * 16;       // padded to 16 elems

  // workspace layout — every segment a multiple of 16 elements (64B aligned)
  int*   rowp  = (int*)d_ws;                        // N+16
  int*   bbase = rowp + (N + 16);                   // NB2+16 (holds NBUCK+1)
  int*   bcnt  = bbase + (NB2 + 16);                // NB2
  int*   bcur  = bcnt + NB2;                        // NB2
  int*   dstc  = bcur + NB2;                        // E
  float* attv  = (float*)(dstc + E);                // E
  float* X     = attv + E;                          // N*64  (pairs aliased at front)
  float* H     = X + (size_t)N * HIDN;              // N*64  (pa/pb aliased at front)
  int2*  pairs = (int2*)X;                          // 2E ints <= N*64 floats
  float* pa    = H;                                 // N   (dead before H written)
  float* pb    = H + N;                             // N

  (void)hipMemsetAsync(bcnt, 0, (size_t)2 * NB2 * sizeof(int), stream);  // bcnt+bcur

  dim3 blk(256);
  const int gridWave = (N + 3) / 4;
  const int gridE    = (E + 255) / 256;
  const int gridGemm = (N + 127) / 128;

  proj_kernel<<<gridWave, blk, 0, stream>>>(hidden, attw, pa, pb, N);
  hist_kernel<<<512, blk, 0, stream>>>(src, bcnt, E, NBUCK);
  scan_buckets<<<1, 1024, 0, stream>>>(bcnt, bbase, rowp, NBUCK, N, E);
  scatter_pairs<<<gridE, blk, 0, stream>>>(src, dst, bbase, bcur, pairs, E);
  build_csr<<<NBUCK, blk, 0, stream>>>(pairs, bbase, rowp, dstc, N);
  att_softmax<<<gridWave, blk, 0, stream>>>(pa, pb, dstc, rowp, attv, N);

  gemm_tiled<INDIM, HIDN, 8><<<gridGemm, blk, 0, stream>>>(features, W0, X, N);
  spmm_elu<HIDN, false><<<gridWave, blk, 0, stream>>>(
      (const float4*)X, attv, dstc, rowp, (float4*)H, N);
  gemm_tiled<HIDN, HIDN, 8><<<gridGemm, blk, 0, stream>>>(H, W1, X, N);
  spmm_elu<HIDN, false><<<gridWave, blk, 0, stream>>>(
      (const float4*)X, attv, dstc, rowp, (float4*)H, N);
  gemm_tiled<HIDN, NCLS_K, 4><<<gridGemm, blk, 0, stream>>>(H, W2, X, N);
  spmm_elu<NCLS_K, true><<<gridWave, blk, 0, stream>>>(
      (const float4*)X, attv, dstc, rowp, (float4*)out, N);
}

// Round 3
// 419.369 us; speedup vs baseline: 1.8114x; 1.8114x over previous
//
#include <hip/hip_runtime.h>
#include <math.h>

#define HIDN 64
#define NCLS_K 32
#define INDIM 256
#define BSHIFT 7            // bucket = src >> 7  (128 src rows per bucket)
#define MAXBUCK 1024        // supports N <= 131072
#define BUCK_CAP 4096       // max edges per bucket (mean 2048, std ~45)

// ---------------- per-node projections: pa = h.att_w[:64], pb = h.att_w[64:]
__global__ __launch_bounds__(256) void proj_kernel(const float* __restrict__ hid,
    const float* __restrict__ attw, float* __restrict__ pa, float* __restrict__ pb, int n) {
  int wid  = (blockIdx.x * blockDim.x + threadIdx.x) >> 6;
  int lane = threadIdx.x & 63;
  if (wid >= n) return;
  float v = hid[(size_t)wid * HIDN + lane];
  float a = v * attw[lane];
  float b = v * attw[HIDN + lane];
  #pragma unroll
  for (int off = 32; off >= 1; off >>= 1) {
    a += __shfl_xor(a, off, 64);
    b += __shfl_xor(b, off, 64);
  }
  if (lane == 0) { pa[wid] = a; pb[wid] = b; }
}

// ---------------- CSR build pass A: bucket histogram
__global__ __launch_bounds__(256) void hist_kernel(const int* __restrict__ src,
    int* __restrict__ bcnt, int e, int nb) {
  __shared__ int h[MAXBUCK];
  for (int j = threadIdx.x; j < MAXBUCK; j += 256) h[j] = 0;
  __syncthreads();
  for (int i = blockIdx.x * 256 + threadIdx.x; i < e; i += gridDim.x * 256)
    atomicAdd(&h[src[i] >> BSHIFT], 1);
  __syncthreads();
  for (int j = threadIdx.x; j < nb; j += 256)
    if (h[j]) atomicAdd(&bcnt[j], h[j]);
}

// ---------------- CSR build: scan bucket counts (single block)
__global__ __launch_bounds__(1024) void scan_buckets(const int* __restrict__ bcnt,
    int* __restrict__ bbase, int* __restrict__ rowp, int nb, int n, int e) {
  __shared__ int sm[1024];
  int tid = threadIdx.x;
  int v = (tid < nb) ? bcnt[tid] : 0;
  sm[tid] = v;
  __syncthreads();
  for (int off = 1; off < 1024; off <<= 1) {
    int t = (tid >= off) ? sm[tid - off] : 0;
    __syncthreads();
    sm[tid] += t;
    __syncthreads();
  }
  if (tid < nb) bbase[tid] = sm[tid] - v;   // exclusive
  if (tid == 0) { bbase[nb] = e; rowp[n] = e; }
}

// ---------------- CSR build pass B: scatter (src,dst) into bucket regions,
// cursor atomics aggregated per block in LDS (fixes 782-counter contention)
__global__ __launch_bounds__(256) void scatter_pairs(const int* __restrict__ src,
    const int* __restrict__ dst, const int* __restrict__ bbase,
    int* __restrict__ bcur, int2* __restrict__ pairs, int e, int nb) {
  __shared__ int h[MAXBUCK];        // block-local counts, then global cursors
  int nper = (e + gridDim.x - 1) / gridDim.x;
  int lo = blockIdx.x * nper;
  int hi = min(e, lo + nper);
  for (int j = threadIdx.x; j < nb; j += 256) h[j] = 0;
  __syncthreads();
  for (int i = lo + threadIdx.x; i < hi; i += 256)
    atomicAdd(&h[src[i] >> BSHIFT], 1);
  __syncthreads();
  for (int j = threadIdx.x; j < nb; j += 256) {
    int c = h[j];
    h[j] = c ? (bbase[j] + atomicAdd(&bcur[j], c)) : 0;   // global range start
  }
  __syncthreads();
  for (int i = lo + threadIdx.x; i < hi; i += 256) {
    int s = src[i];
    int pos = atomicAdd(&h[s >> BSHIFT], 1);
    pairs[pos] = make_int2(s, dst[i]);
  }
}

// ---------------- CSR build pass C: per-bucket LDS counting sort -> rowp, dstc
__global__ __launch_bounds__(256) void build_csr(const int2* __restrict__ pairs,
    const int* __restrict__ bbase, int* __restrict__ rowp,
    int* __restrict__ dstc, int n) {
  __shared__ int hist[128];
  __shared__ int cur[128];
  __shared__ int ord[BUCK_CAP];
  int b = blockIdx.x;
  int tid = threadIdx.x;
  int base = bbase[b];
  int m = bbase[b + 1] - base;
  if (tid < 128) hist[tid] = 0;
  __syncthreads();
  for (int i = tid; i < m; i += 256) atomicAdd(&hist[pairs[base + i].x & 127], 1);
  __syncthreads();
  int own = (tid < 128) ? hist[tid] : 0;
  for (int off = 1; off < 128; off <<= 1) {          // inclusive scan of 128
    int t = (tid < 128 && tid >= off) ? hist[tid - off] : 0;
    __syncthreads();
    if (tid < 128) hist[tid] += t;
    __syncthreads();
  }
  if (tid < 128) {
    int excl = hist[tid] - own;
    cur[tid] = excl;
    int s = (b << BSHIFT) + tid;
    if (s < n) rowp[s] = base + excl;
  }
  __syncthreads();
  for (int i = tid; i < m; i += 256) {
    int2 pr = pairs[base + i];
    int pos = atomicAdd(&cur[pr.x & 127], 1);
    ord[pos] = pr.y;
  }
  __syncthreads();
  for (int i = tid; i < m; i += 256) dstc[base + i] = ord[i];
}

// ---------------- per-row (src-segmented) edge softmax, wave per row
__global__ __launch_bounds__(256) void att_softmax(const float* __restrict__ pa,
    const float* __restrict__ pb, const int* __restrict__ dstc,
    const int* __restrict__ rowp, float* __restrict__ attv, int n) {
  int wid  = (blockIdx.x * blockDim.x + threadIdx.x) >> 6;
  int lane = threadIdx.x & 63;
  if (wid >= n) return;
  int start = rowp[wid], end = rowp[wid + 1];
  if (start == end) return;
  float pai = pa[wid];
  float m = -3.0e38f;
  for (int base = start; base < end; base += 64) {
    int e = base + lane;
    float s = -3.0e38f;
    if (e < end) {
      float v = pai + pb[dstc[e]];
      s = v > 0.f ? v : 0.01f * v;        // leaky_relu slope 0.01
      attv[e] = s;
    }
    m = fmaxf(m, s);
  }
  #pragma unroll
  for (int off = 32; off >= 1; off >>= 1) m = fmaxf(m, __shfl_xor(m, off, 64));
  float sum = 0.f;
  for (int base = start; base < end; base += 64) {
    int e = base + lane;
    float ex = 0.f;
    if (e < end) { ex = expf(attv[e] - m); attv[e] = ex; }
    sum += ex;
  }
  #pragma unroll
  for (int off = 32; off >= 1; off >>= 1) sum += __shfl_xor(sum, off, 64);
  float inv = 1.f / sum;
  for (int base = start; base < end; base += 64) {
    int e = base + lane;
    if (e < end) attv[e] *= inv;
  }
}

// ---------------- tiled dense GEMM: X[n x TJ] = A[n x K] @ W[K x TJ]
// 128-row x TJ-col block tile, 4 x TN per-thread tile, KC=64 k-chunks in LDS.
template <int K, int TJ, int TN>
__global__ __launch_bounds__(256) void gemm_tiled(const float* __restrict__ A,
    const float* __restrict__ W, float* __restrict__ X, int n) {
  constexpr int KC = 64;
  constexpr int TR = 128;
  constexpr int CG = TJ / TN;                 // 8 column groups
  __shared__ float Hs[TR][KC + 1];            // +1 pad: conflict-free scalar reads
  __shared__ float Ws[KC][TJ];
  const int tid  = threadIdx.x;
  const int row0 = blockIdx.x * TR;
  const int tx = tid % CG;
  const int ty = tid / CG;                    // 0..31
  float acc[4][TN];
  #pragma unroll
  for (int i = 0; i < 4; ++i)
    #pragma unroll
    for (int j = 0; j < TN; ++j) acc[i][j] = 0.f;

  for (int kc = 0; kc < K; kc += KC) {
    #pragma unroll
    for (int p = 0; p < (TR * KC) / (4 * 256); ++p) {   // 8 float4 per thread
      int f = tid + p * 256;
      int r = f >> 4;
      int q = f & 15;
      float4 h4 = make_float4(0.f, 0.f, 0.f, 0.f);
      if (row0 + r < n)
        h4 = *reinterpret_cast<const float4*>(A + (size_t)(row0 + r) * K + kc + q * 4);
      Hs[r][q * 4 + 0] = h4.x;
      Hs[r][q * 4 + 1] = h4.y;
      Hs[r][q * 4 + 2] = h4.z;
      Hs[r][q * 4 + 3] = h4.w;
    }
    #pragma unroll
    for (int p = 0; p < (KC * TJ) / (4 * 256); ++p) {
      int f = tid + p * 256;
      reinterpret_cast<float4*>(&Ws[0][0])[f] =
          reinterpret_cast<const float4*>(W + (size_t)kc * TJ)[f];
    }
    __syncthreads();
    for (int kk = 0; kk < KC; ++kk) {
      float a0 = Hs[ty * 4 + 0][kk];
      float a1 = Hs[ty * 4 + 1][kk];
      float a2 = Hs[ty * 4 + 2][kk];
      float a3 = Hs[ty * 4 + 3][kk];
      float bb[TN];
      #pragma unroll
      for (int j = 0; j < TN; j += 4) {
        float4 b4 = *reinterpret_cast<const float4*>(&Ws[kk][tx * TN + j]);
        bb[j] = b4.x; bb[j + 1] = b4.y; bb[j + 2] = b4.z; bb[j + 3] = b4.w;
      }
      #pragma unroll
      for (int j = 0; j < TN; ++j) {
        acc[0][j] += a0 * bb[j];
        acc[1][j] += a1 * bb[j];
        acc[2][j] += a2 * bb[j];
        acc[3][j] += a3 * bb[j];
      }
    }
    __syncthreads();
  }
  #pragma unroll
  for (int i = 0; i < 4; ++i) {
    int r = row0 + ty * 4 + i;
    if (r < n) {
      #pragma unroll
      for (int j = 0; j < TN; j += 4) {
        float4 o = make_float4(acc[i][j], acc[i][j + 1], acc[i][j + 2], acc[i][j + 3]);
        *reinterpret_cast<float4*>(X + (size_t)r * TJ + tx * TN + j) = o;
      }
    }
  }
}

// ---------------- SpMM + ELU (+ fused log_softmax), wave/row, float4 gathers
template <int J, bool FINAL>
__global__ __launch_bounds__(256) void spmm_elu(const float4* __restrict__ Xv,
    const float* __restrict__ attv, const int* __restrict__ dstc,
    const int* __restrict__ rowp, float4* __restrict__ outv, int n) {
  constexpr int CW  = J / 4;            // float4 col groups: 16 (J=64) / 8 (J=32)
  constexpr int EPW = 64 / CW;          // edges in flight per step: 4 / 8
  int wid  = (blockIdx.x * blockDim.x + threadIdx.x) >> 6;
  int lane = threadIdx.x & 63;
  if (wid >= n) return;
  int start = rowp[wid], end = rowp[wid + 1];
  int col  = lane & (CW - 1);
  int esub = lane / CW;
  float4 acc0 = make_float4(0.f, 0.f, 0.f, 0.f);
  float4 acc1 = make_float4(0.f, 0.f, 0.f, 0.f);
  for (int base = start; base < end; base += 64) {
    int e = base + lane;
    float av = 0.f; int dv = 0;
    if (e < end) { av = attv[e]; dv = dstc[e]; }
    int cnt = min(64, end - base);
    for (int t = 0; t < cnt; t += 2 * EPW) {
      {
        int mi = t + esub;                 // always <= 63
        float bv = __shfl(av, mi);
        int   d  = __shfl(dv, mi);
        float4 x = Xv[(size_t)d * CW + col];
        acc0.x += bv * x.x; acc0.y += bv * x.y;
        acc0.z += bv * x.z; acc0.w += bv * x.w;
      }
      {
        int mi = t + EPW + esub;           // always <= 63; av=0 beyond cnt
        float bv = __shfl(av, mi);
        int   d  = __shfl(dv, mi);
        float4 x = Xv[(size_t)d * CW + col];
        acc1.x += bv * x.x; acc1.y += bv * x.y;
        acc1.z += bv * x.z; acc1.w += bv * x.w;
      }
    }
  }
  float4 acc = make_float4(acc0.x + acc1.x, acc0.y + acc1.y,
                           acc0.z + acc1.z, acc0.w + acc1.w);
  #pragma unroll
  for (int off = CW; off < 64; off <<= 1) {     // reduce across edge sub-groups
    acc.x += __shfl_xor(acc.x, off);
    acc.y += __shfl_xor(acc.y, off);
    acc.z += __shfl_xor(acc.z, off);
    acc.w += __shfl_xor(acc.w, off);
  }
  acc.x = acc.x > 0.f ? acc.x : (expf(acc.x) - 1.f);   // ELU
  acc.y = acc.y > 0.f ? acc.y : (expf(acc.y) - 1.f);
  acc.z = acc.z > 0.f ? acc.z : (expf(acc.z) - 1.f);
  acc.w = acc.w > 0.f ? acc.w : (expf(acc.w) - 1.f);
  if (!FINAL) {
    if (lane < CW) outv[(size_t)wid * CW + col] = acc;
  } else {
    float m = fmaxf(fmaxf(acc.x, acc.y), fmaxf(acc.z, acc.w));
    #pragma unroll
    for (int off = 1; off < CW; off <<= 1) m = fmaxf(m, __shfl_xor(m, off));
    float s = expf(acc.x - m) + expf(acc.y - m) + expf(acc.z - m) + expf(acc.w - m);
    #pragma unroll
    for (int off = 1; off < CW; off <<= 1) s += __shfl_xor(s, off);
    float lg = m + logf(s);
    acc.x -= lg; acc.y -= lg; acc.z -= lg; acc.w -= lg;
    if (lane < CW) outv[(size_t)wid * CW + col] = acc;
  }
}

extern "C" void kernel_launch(void* const* d_in, const int* in_sizes, int n_in,
                              void* d_out, int out_size, void* d_ws, size_t ws_size,
                              hipStream_t stream) {
  const float* features = (const float*)d_in[0];
  const float* hidden   = (const float*)d_in[1];
  const int*   adj      = (const int*)d_in[2];
  const float* W0       = (const float*)d_in[3];
  const float* W1       = (const float*)d_in[4];
  const float* W2       = (const float*)d_in[5];
  const float* attw     = (const float*)d_in[6];
  float* out = (float*)d_out;

  const int N = in_sizes[1] / HIDN;   // 100000
  const int E = in_sizes[2] / 2;      // 1600000
  const int* src = adj;
  const int* dst = adj + E;
  const int NBUCK = (N + 127) >> BSHIFT;            // 782
  const int NB2   = ((NBUCK + 15) / 16) * 16;       // padded to 16 elems

  // workspace layout — every segment a multiple of 16 elements (64B aligned)
  int*   rowp  = (int*)d_ws;                        // N+16
  int*   bbase = rowp + (N + 16);                   // NB2+16 (holds NBUCK+1)
  int*   bcnt  = bbase + (NB2 + 16);                // NB2
  int*   bcur  = bcnt + NB2;                        // NB2
  int*   dstc  = bcur + NB2;                        // E
  float* attv  = (float*)(dstc + E);                // E
  float* X     = attv + E;                          // N*64  (pairs aliased at front)
  float* H     = X + (size_t)N * HIDN;              // N*64  (pa/pb aliased at front)
  int2*  pairs = (int2*)X;                          // 2E ints <= N*64 floats
  float* pa    = H;                                 // N   (dead before H written)
  float* pb    = H + N;                             // N

  (void)hipMemsetAsync(bcnt, 0, (size_t)2 * NB2 * sizeof(int), stream);  // bcnt+bcur

  dim3 blk(256);
  const int gridWave = (N + 3) / 4;
  const int gridE    = (E + 255) / 256;
  const int gridGemm = (N + 127) / 128;

  proj_kernel<<<gridWave, blk, 0, stream>>>(hidden, attw, pa, pb, N);
  hist_kernel<<<512, blk, 0, stream>>>(src, bcnt, E, NBUCK);
  scan_buckets<<<1, 1024, 0, stream>>>(bcnt, bbase, rowp, NBUCK, N, E);
  scatter_pairs<<<512, blk, 0, stream>>>(src, dst, bbase, bcur, pairs, E, NBUCK);
  build_csr<<<NBUCK, blk, 0, stream>>>(pairs, bbase, rowp, dstc, N);
  att_softmax<<<gridWave, blk, 0, stream>>>(pa, pb, dstc, rowp, attv, N);

  gemm_tiled<INDIM, HIDN, 8><<<gridGemm, blk, 0, stream>>>(features, W0, X, N);
  spmm_elu<HIDN, false><<<gridWave, blk, 0, stream>>>(
      (const float4*)X, attv, dstc, rowp, (float4*)H, N);
  gemm_tiled<HIDN, HIDN, 8><<<gridGemm, blk, 0, stream>>>(H, W1, X, N);
  spmm_elu<HIDN, false><<<gridWave, blk, 0, stream>>>(
      (const float4*)X, attv, dstc, rowp, (float4*)H, N);
  gemm_tiled<HIDN, NCLS_K, 4><<<gridGemm, blk, 0, stream>>>(H, W2, X, N);
  spmm_elu<NCLS_K, true><<<gridWave, blk, 0, stream>>>(
      (const float4*)X, attv, dstc, rowp, (float4*)out, N);
}

// Round 4
// 417.140 us; speedup vs baseline: 1.8210x; 1.0053x over previous
//
#include <hip/hip_runtime.h>
#include <math.h>

#define HIDN 64
#define NCLS_K 32
#define INDIM 256
#define BSHIFT 7            // bucket = src >> 7  (128 src rows per bucket)
#define MAXBUCK 1024        // supports N <= 131072
#define BUCK_CAP 4096       // max edges per bucket (mean 2048, std ~45)
#define DSTBITS 17          // dst fits 17 bits (N < 131072); key = (local<<17)|dst

// ---------------- per-node projections: pa = h.att_w[:64], pb = h.att_w[64:]
__global__ __launch_bounds__(256) void proj_kernel(const float* __restrict__ hid,
    const float* __restrict__ attw, float* __restrict__ pa, float* __restrict__ pb, int n) {
  int wid  = (blockIdx.x * blockDim.x + threadIdx.x) >> 6;
  int lane = threadIdx.x & 63;
  if (wid >= n) return;
  float v = hid[(size_t)wid * HIDN + lane];
  float a = v * attw[lane];
  float b = v * attw[HIDN + lane];
  #pragma unroll
  for (int off = 32; off >= 1; off >>= 1) {
    a += __shfl_xor(a, off, 64);
    b += __shfl_xor(b, off, 64);
  }
  if (lane == 0) { pa[wid] = a; pb[wid] = b; }
}

// ---------------- CSR build pass A: bucket histogram
__global__ __launch_bounds__(256) void hist_kernel(const int* __restrict__ src,
    int* __restrict__ bcnt, int e, int nb) {
  __shared__ int h[MAXBUCK];
  for (int j = threadIdx.x; j < MAXBUCK; j += 256) h[j] = 0;
  __syncthreads();
  for (int i = blockIdx.x * 256 + threadIdx.x; i < e; i += gridDim.x * 256)
    atomicAdd(&h[src[i] >> BSHIFT], 1);
  __syncthreads();
  for (int j = threadIdx.x; j < nb; j += 256)
    if (h[j]) atomicAdd(&bcnt[j], h[j]);
}

// ---------------- CSR build: scan bucket counts (single block)
__global__ __launch_bounds__(1024) void scan_buckets(const int* __restrict__ bcnt,
    int* __restrict__ bbase, int* __restrict__ rowp, int nb, int n, int e) {
  __shared__ int sm[1024];
  int tid = threadIdx.x;
  int v = (tid < nb) ? bcnt[tid] : 0;
  sm[tid] = v;
  __syncthreads();
  for (int off = 1; off < 1024; off <<= 1) {
    int t = (tid >= off) ? sm[tid - off] : 0;
    __syncthreads();
    sm[tid] += t;
    __syncthreads();
  }
  if (tid < nb) bbase[tid] = sm[tid] - v;   // exclusive
  if (tid == 0) { bbase[nb] = e; rowp[n] = e; }
}

// ---------------- CSR build pass B: scatter packed (local,dst) keys into
// bucket regions; cursor atomics aggregated per block in LDS
__global__ __launch_bounds__(256) void scatter_pairs(const int* __restrict__ src,
    const int* __restrict__ dst, const int* __restrict__ bbase,
    int* __restrict__ bcur, int* __restrict__ pairs, int e, int nb) {
  __shared__ int h[MAXBUCK];        // block-local counts, then global cursors
  int nper = (e + gridDim.x - 1) / gridDim.x;
  int lo = blockIdx.x * nper;
  int hi = min(e, lo + nper);
  for (int j = threadIdx.x; j < nb; j += 256) h[j] = 0;
  __syncthreads();
  for (int i = lo + threadIdx.x; i < hi; i += 256)
    atomicAdd(&h[src[i] >> BSHIFT], 1);
  __syncthreads();
  for (int j = threadIdx.x; j < nb; j += 256) {
    int c = h[j];
    h[j] = c ? (bbase[j] + atomicAdd(&bcur[j], c)) : 0;   // global range start
  }
  __syncthreads();
  for (int i = lo + threadIdx.x; i < hi; i += 256) {
    int s = src[i];
    int pos = atomicAdd(&h[s >> BSHIFT], 1);
    pairs[pos] = ((s & 127) << DSTBITS) | dst[i];
  }
}

// ---------------- CSR build pass C: per-bucket LDS counting sort -> rowp, dstc
__global__ __launch_bounds__(256) void build_csr(const int* __restrict__ pairs,
    const int* __restrict__ bbase, int* __restrict__ rowp,
    int* __restrict__ dstc, int n) {
  __shared__ int hist[128];
  __shared__ int cur[128];
  __shared__ int ord[BUCK_CAP];
  int b = blockIdx.x;
  int tid = threadIdx.x;
  int base = bbase[b];
  int m = bbase[b + 1] - base;
  if (tid < 128) hist[tid] = 0;
  __syncthreads();
  for (int i = tid; i < m; i += 256)
    atomicAdd(&hist[pairs[base + i] >> DSTBITS], 1);
  __syncthreads();
  int own = (tid < 128) ? hist[tid] : 0;
  for (int off = 1; off < 128; off <<= 1) {          // inclusive scan of 128
    int t = (tid < 128 && tid >= off) ? hist[tid - off] : 0;
    __syncthreads();
    if (tid < 128) hist[tid] += t;
    __syncthreads();
  }
  if (tid < 128) {
    int excl = hist[tid] - own;
    cur[tid] = excl;
    int s = (b << BSHIFT) + tid;
    if (s < n) rowp[s] = base + excl;
  }
  __syncthreads();
  for (int i = tid; i < m; i += 256) {
    int key = pairs[base + i];
    int pos = atomicAdd(&cur[key >> DSTBITS], 1);
    ord[pos] = key & ((1 << DSTBITS) - 1);
  }
  __syncthreads();
  for (int i = tid; i < m; i += 256) dstc[base + i] = ord[i];
}

// ---------------- per-row (src-segmented) edge softmax, wave per row
__global__ __launch_bounds__(256) void att_softmax(const float* __restrict__ pa,
    const float* __restrict__ pb, const int* __restrict__ dstc,
    const int* __restrict__ rowp, float* __restrict__ attv, int n) {
  int wid  = (blockIdx.x * blockDim.x + threadIdx.x) >> 6;
  int lane = threadIdx.x & 63;
  if (wid >= n) return;
  int start = rowp[wid], end = rowp[wid + 1];
  if (start == end) return;
  float pai = pa[wid];
  float m = -3.0e38f;
  for (int base = start; base < end; base += 64) {
    int e = base + lane;
    float s = -3.0e38f;
    if (e < end) {
      float v = pai + pb[dstc[e]];
      s = v > 0.f ? v : 0.01f * v;        // leaky_relu slope 0.01
      attv[e] = s;
    }
    m = fmaxf(m, s);
  }
  #pragma unroll
  for (int off = 32; off >= 1; off >>= 1) m = fmaxf(m, __shfl_xor(m, off, 64));
  float sum = 0.f;
  for (int base = start; base < end; base += 64) {
    int e = base + lane;
    float ex = 0.f;
    if (e < end) { ex = expf(attv[e] - m); attv[e] = ex; }
    sum += ex;
  }
  #pragma unroll
  for (int off = 32; off >= 1; off >>= 1) sum += __shfl_xor(sum, off, 64);
  float inv = 1.f / sum;
  for (int base = start; base < end; base += 64) {
    int e = base + lane;
    if (e < end) attv[e] *= inv;
  }
}

// ---------------- tiled dense GEMM: X[n x TJ] = A[n x K] @ W[K x TJ]
// 64-row tile, KC=64, per-thread 2 x (TJ/8) micro-tile. LDS ~33KB -> 4 blk/CU.
template <int K, int TJ>
__global__ __launch_bounds__(256) void gemm_tiled(const float* __restrict__ A,
    const float* __restrict__ W, float* __restrict__ X, int n) {
  constexpr int KC = 64;
  constexpr int TR = 64;
  constexpr int TN = TJ / 8;                  // 8 (TJ=64) or 4 (TJ=32)
  __shared__ float Hs[TR][KC + 1];
  __shared__ float Ws[KC][TJ];
  const int tid  = threadIdx.x;
  const int row0 = blockIdx.x * TR;
  const int tx = tid & 7;                     // 8 column groups
  const int ty = tid >> 3;                    // 0..31 -> 2 rows each
  float acc[2][TN];
  #pragma unroll
  for (int i = 0; i < 2; ++i)
    #pragma unroll
    for (int j = 0; j < TN; ++j) acc[i][j] = 0.f;

  for (int kc = 0; kc < K; kc += KC) {
    #pragma unroll
    for (int p = 0; p < (TR * KC) / (4 * 256); ++p) {   // 4 float4 per thread
      int f = tid + p * 256;
      int r = f >> 4;
      int q = f & 15;
      float4 h4 = make_float4(0.f, 0.f, 0.f, 0.f);
      if (row0 + r < n)
        h4 = *reinterpret_cast<const float4*>(A + (size_t)(row0 + r) * K + kc + q * 4);
      Hs[r][q * 4 + 0] = h4.x;
      Hs[r][q * 4 + 1] = h4.y;
      Hs[r][q * 4 + 2] = h4.z;
      Hs[r][q * 4 + 3] = h4.w;
    }
    #pragma unroll
    for (int p = 0; p < (KC * TJ) / (4 * 256); ++p) {
      int f = tid + p * 256;
      int r = f / (TJ / 4);
      int q = f % (TJ / 4);
      *reinterpret_cast<float4*>(&Ws[r][q * 4]) =
          *reinterpret_cast<const float4*>(W + (size_t)(kc + r) * TJ + q * 4);
    }
    __syncthreads();
    #pragma unroll 4
    for (int kk = 0; kk < KC; ++kk) {
      float a0 = Hs[ty * 2 + 0][kk];
      float a1 = Hs[ty * 2 + 1][kk];
      float bb[TN];
      #pragma unroll
      for (int j = 0; j < TN; j += 4) {
        float4 b4 = *reinterpret_cast<const float4*>(&Ws[kk][tx * TN + j]);
        bb[j] = b4.x; bb[j + 1] = b4.y; bb[j + 2] = b4.z; bb[j + 3] = b4.w;
      }
      #pragma unroll
      for (int j = 0; j < TN; ++j) {
        acc[0][j] += a0 * bb[j];
        acc[1][j] += a1 * bb[j];
      }
    }
    __syncthreads();
  }
  #pragma unroll
  for (int i = 0; i < 2; ++i) {
    int r = row0 + ty * 2 + i;
    if (r < n) {
      #pragma unroll
      for (int j = 0; j < TN; j += 4) {
        float4 o = make_float4(acc[i][j], acc[i][j + 1], acc[i][j + 2], acc[i][j + 3]);
        *reinterpret_cast<float4*>(X + (size_t)r * TJ + tx * TN + j) = o;
      }
    }
  }
}

// ---------------- SpMM + ELU (+ fused log_softmax), wave/row, float4 gathers
template <int J, bool FINAL>
__global__ __launch_bounds__(256) void spmm_elu(const float4* __restrict__ Xv,
    const float* __restrict__ attv, const int* __restrict__ dstc,
    const int* __restrict__ rowp, float4* __restrict__ outv, int n) {
  constexpr int CW  = J / 4;            // float4 col groups: 16 (J=64) / 8 (J=32)
  constexpr int EPW = 64 / CW;          // edges in flight per step: 4 / 8
  int wid  = (blockIdx.x * blockDim.x + threadIdx.x) >> 6;
  int lane = threadIdx.x & 63;
  if (wid >= n) return;
  int start = rowp[wid], end = rowp[wid + 1];
  int col  = lane & (CW - 1);
  int esub = lane / CW;
  float4 acc0 = make_float4(0.f, 0.f, 0.f, 0.f);
  float4 acc1 = make_float4(0.f, 0.f, 0.f, 0.f);
  for (int base = start; base < end; base += 64) {
    int e = base + lane;
    float av = 0.f; int dv = 0;
    if (e < end) { av = attv[e]; dv = dstc[e]; }
    int cnt = min(64, end - base);
    for (int t = 0; t < cnt; t += 2 * EPW) {
      {
        int mi = t + esub;                 // always <= 63
        float bv = __shfl(av, mi);
        int   d  = __shfl(dv, mi);
        float4 x = Xv[(size_t)d * CW + col];
        acc0.x += bv * x.x; acc0.y += bv * x.y;
        acc0.z += bv * x.z; acc0.w += bv * x.w;
      }
      {
        int mi = t + EPW + esub;           // always <= 63; av=0 beyond cnt
        float bv = __shfl(av, mi);
        int   d  = __shfl(dv, mi);
        float4 x = Xv[(size_t)d * CW + col];
        acc1.x += bv * x.x; acc1.y += bv * x.y;
        acc1.z += bv * x.z; acc1.w += bv * x.w;
      }
    }
  }
  float4 acc = make_float4(acc0.x + acc1.x, acc0.y + acc1.y,
                           acc0.z + acc1.z, acc0.w + acc1.w);
  #pragma unroll
  for (int off = CW; off < 64; off <<= 1) {     // reduce across edge sub-groups
    acc.x += __shfl_xor(acc.x, off);
    acc.y += __shfl_xor(acc.y, off);
    acc.z += __shfl_xor(acc.z, off);
    acc.w += __shfl_xor(acc.w, off);
  }
  acc.x = acc.x > 0.f ? acc.x : (expf(acc.x) - 1.f);   // ELU
  acc.y = acc.y > 0.f ? acc.y : (expf(acc.y) - 1.f);
  acc.z = acc.z > 0.f ? acc.z : (expf(acc.z) - 1.f);
  acc.w = acc.w > 0.f ? acc.w : (expf(acc.w) - 1.f);
  if (!FINAL) {
    if (lane < CW) outv[(size_t)wid * CW + col] = acc;
  } else {
    float m = fmaxf(fmaxf(acc.x, acc.y), fmaxf(acc.z, acc.w));
    #pragma unroll
    for (int off = 1; off < CW; off <<= 1) m = fmaxf(m, __shfl_xor(m, off));
    float s = expf(acc.x - m) + expf(acc.y - m) + expf(acc.z - m) + expf(acc.w - m);
    #pragma unroll
    for (int off = 1; off < CW; off <<= 1) s += __shfl_xor(s, off);
    float lg = m + logf(s);
    acc.x -= lg; acc.y -= lg; acc.z -= lg; acc.w -= lg;
    if (lane < CW) outv[(size_t)wid * CW + col] = acc;
  }
}

extern "C" void kernel_launch(void* const* d_in, const int* in_sizes, int n_in,
                              void* d_out, int out_size, void* d_ws, size_t ws_size,
                              hipStream_t stream) {
  const float* features = (const float*)d_in[0];
  const float* hidden   = (const float*)d_in[1];
  const int*   adj      = (const int*)d_in[2];
  const float* W0       = (const float*)d_in[3];
  const float* W1       = (const float*)d_in[4];
  const float* W2       = (const float*)d_in[5];
  const float* attw     = (const float*)d_in[6];
  float* out = (float*)d_out;

  const int N = in_sizes[1] / HIDN;   // 100000
  const int E = in_sizes[2] / 2;      // 1600000
  const int* src = adj;
  const int* dst = adj + E;
  const int NBUCK = (N + 127) >> BSHIFT;            // 782
  const int NB2   = ((NBUCK + 15) / 16) * 16;       // padded to 16 elems

  // workspace layout — every segment a multiple of 16 elements (64B aligned)
  int*   rowp  = (int*)d_ws;                        // N+16
  int*   bbase = rowp + (N + 16);                   // NB2+16 (holds NBUCK+1)
  int*   bcnt  = bbase + (NB2 + 16);                // NB2
  int*   bcur  = bcnt + NB2;                        // NB2
  int*   dstc  = bcur + NB2;                        // E
  float* attv  = (float*)(dstc + E);                // E
  float* X     = attv + E;                          // N*64  (pairs aliased at front)
  float* H     = X + (size_t)N * HIDN;              // N*64  (pa/pb aliased at front)
  int*   pairs = (int*)X;                           // E ints <= N*64 floats
  float* pa    = H;                                 // N   (dead before H written)
  float* pb    = H + N;                             // N

  (void)hipMemsetAsync(bcnt, 0, (size_t)2 * NB2 * sizeof(int), stream);  // bcnt+bcur

  dim3 blk(256);
  const int gridWave = (N + 3) / 4;
  const int gridGemm = (N + 63) / 64;

  proj_kernel<<<gridWave, blk, 0, stream>>>(hidden, attw, pa, pb, N);
  hist_kernel<<<512, blk, 0, stream>>>(src, bcnt, E, NBUCK);
  scan_buckets<<<1, 1024, 0, stream>>>(bcnt, bbase, rowp, NBUCK, N, E);
  scatter_pairs<<<128, blk, 0, stream>>>(src, dst, bbase, bcur, pairs, E, NBUCK);
  build_csr<<<NBUCK, blk, 0, stream>>>(pairs, bbase, rowp, dstc, N);
  att_softmax<<<gridWave, blk, 0, stream>>>(pa, pb, dstc, rowp, attv, N);

  gemm_tiled<INDIM, HIDN><<<gridGemm, blk, 0, stream>>>(features, W0, X, N);
  spmm_elu<HIDN, false><<<gridWave, blk, 0, stream>>>(
      (const float4*)X, attv, dstc, rowp, (float4*)H, N);
  gemm_tiled<HIDN, HIDN><<<gridGemm, blk, 0, stream>>>(H, W1, X, N);
  spmm_elu<HIDN, false><<<gridWave, blk, 0, stream>>>(
      (const float4*)X, attv, dstc, rowp, (float4*)H, N);
  gemm_tiled<HIDN, NCLS_K><<<gridGemm, blk, 0, stream>>>(H, W2, X, N);
  spmm_elu<NCLS_K, true><<<gridWave, blk, 0, stream>>>(
      (const float4*)X, attv, dstc, rowp, (float4*)out, N);
}